// Round 5
// baseline (820.590 us; speedup 1.0000x reference)
//
#include <hip/hip_runtime.h>
#include <cstdint>

#define NROWS 2048
#define DDIM  1024
#define NCLS  128000
#define BM 256
#define BN 256
#define BK 64
#define RTILES (NROWS / BM)   // 8
#define CTILES (NCLS / BN)    // 500
#define KTILES (DDIM / BK)    // 16

typedef __attribute__((ext_vector_type(8))) short bf16x8;
typedef __attribute__((ext_vector_type(4))) float f32x4;

__device__ __forceinline__ unsigned short f2bf(float x) {
    unsigned int u = __float_as_uint(x);
    u += 0x7fffu + ((u >> 16) & 1u);   // RNE
    return (unsigned short)(u >> 16);
}

__device__ __forceinline__ uint4 pack8(float4 a, float4 b) {
    uint4 r;
    r.x = (unsigned)f2bf(a.x) | ((unsigned)f2bf(a.y) << 16);
    r.y = (unsigned)f2bf(a.z) | ((unsigned)f2bf(a.w) << 16);
    r.z = (unsigned)f2bf(b.x) | ((unsigned)f2bf(b.y) << 16);
    r.w = (unsigned)f2bf(b.z) | ((unsigned)f2bf(b.w) << 16);
    return r;
}

__device__ __forceinline__ void async_load16(unsigned short* lds, const unsigned short* g) {
    __builtin_amdgcn_global_load_lds(
        (const __attribute__((address_space(1))) unsigned int*)(uintptr_t)g,
        (__attribute__((address_space(3))) unsigned int*)(uintptr_t)lds,
        16, 0, 0);
}

// plain row-major f32 -> bf16
__global__ void convert_bf16(const float* __restrict__ src,
                             unsigned short* __restrict__ dst, long long n8) {
    for (long long idx = blockIdx.x * 256LL + threadIdx.x; idx < n8;
         idx += (long long)gridDim.x * 256) {
        const float* p = src + idx * 8;
        float4 v0 = *(const float4*)p;
        float4 v1 = *(const float4*)(p + 4);
        *(uint4*)(dst + idx * 8) = pack8(v0, v1);
    }
}

// ---- 16 MFMA of one C-quadrant (static reg indices per rule #20) ----------
template<int MH, int NH>
__device__ __forceinline__ void quad(f32x4 (&acc)[8][4], bf16x8 (&ar)[4][2], bf16x8 (&br)[4][2]) {
    __builtin_amdgcn_s_setprio(1);
#pragma unroll
    for (int ks = 0; ks < 2; ++ks)
#pragma unroll
        for (int mi = 0; mi < 4; ++mi)
#pragma unroll
            for (int nj = 0; nj < 2; ++nj)
                acc[MH*4+mi][NH*2+nj] = __builtin_amdgcn_mfma_f32_16x16x32_bf16(
                    ar[mi][ks], br[NH*2+nj][ks], acc[MH*4+mi][NH*2+nj], 0, 0, 0);
    __builtin_amdgcn_s_setprio(0);
}

__device__ __forceinline__ void loadAhalf(bf16x8 (&ar)[4][2], const unsigned short* buf,
                                          int arow, int xo0, int xo1, int mh) {
#pragma unroll
    for (int mi = 0; mi < 4; ++mi) {
        ar[mi][0] = *(const bf16x8*)&buf[arow + (mh*4+mi)*1024 + xo0];
        ar[mi][1] = *(const bf16x8*)&buf[arow + (mh*4+mi)*1024 + xo1];
    }
}

template<int NH>
__device__ __forceinline__ void loadBpair(bf16x8 (&br)[4][2], const unsigned short* buf,
                                          int brl, int xo0, int xo1) {
#pragma unroll
    for (int nj = 0; nj < 2; ++nj) {
        br[NH*2+nj][0] = *(const bf16x8*)&buf[brl + (NH*2+nj)*1024 + xo0];
        br[NH*2+nj][1] = *(const bf16x8*)&buf[brl + (NH*2+nj)*1024 + xo1];
    }
}

#define BAR() do { __builtin_amdgcn_sched_barrier(0); __builtin_amdgcn_s_barrier(); \
                   __builtin_amdgcn_sched_barrier(0); } while (0)
#define VMCNT0() asm volatile("s_waitcnt vmcnt(0)" ::: "memory")
#define VMCNT8() asm volatile("s_waitcnt vmcnt(8)" ::: "memory")
#define VMNONE() ((void)0)

__global__ __launch_bounds__(512, 2) void gemm8(
    const unsigned short* __restrict__ A,   // [NROWS][DDIM] bf16 row-major
    const unsigned short* __restrict__ B,   // [NCLS][DDIM] bf16 row-major
    const float* __restrict__ bias,
    const long long* __restrict__ target,
    float* __restrict__ partials,           // [NROWS][CTILES]
    float* __restrict__ tlogit)             // [NROWS]
{
    __shared__ __align__(16) unsigned short Abuf[2][BM * BK];  // 2 x 32 KiB
    __shared__ __align__(16) unsigned short Bbuf[2][BN * BK];  // 2 x 32 KiB

    // XCD-bijective swizzle (4000 % 8 == 0); row-tiles consecutive per XCD.
    const int cpx = (RTILES * CTILES) / 8;   // 500
    int wg  = blockIdx.x;
    int swz = (wg & 7) * cpx + (wg >> 3);
    const int rt = swz & (RTILES - 1);
    const int ct = swz >> 3;
    const int brow = rt * BM;
    const int bcol = ct * BN;

    const int tid  = threadIdx.x;
    const int lane = tid & 63;
    const int wid  = tid >> 6;   // 0..7
    const int wr = wid >> 2;     // 0..1  (M half)
    const int wc = wid & 3;      // 0..3  (N quarter)

    // ---- staging: linear LDS dest, XOR-swizzled global source (rule #21)
    const int lrow = lane >> 3;                       // 0..7
    const int c8   = ((lane & 7) ^ lrow) * 8;         // swizzled 16B-chunk (bf16 units)
    const unsigned short* Asrc = A + (size_t)(brow + wid * 16 + lrow) * DDIM + c8;
    const unsigned short* Bsrc = B + (size_t)(bcol + wid * 16 + lrow) * DDIM + c8;
    const int dstb = wid * 1024;                      // ushort units within 16KiB half

#define STAGEA(kt, h, bi) do { \
    const unsigned short* _s = Asrc + (size_t)((h) * 128) * DDIM + (kt) * BK; \
    async_load16(&Abuf[bi][(h) * 8192 + dstb],       _s); \
    async_load16(&Abuf[bi][(h) * 8192 + dstb + 512], _s + 8 * DDIM); } while (0)
#define STAGEB(kt, h, bi) do { \
    const unsigned short* _s = Bsrc + (size_t)((h) * 128) * DDIM + (kt) * BK; \
    async_load16(&Bbuf[bi][(h) * 8192 + dstb],       _s); \
    async_load16(&Bbuf[bi][(h) * 8192 + dstb + 512], _s + 8 * DDIM); } while (0)

    // ---- fragment read addressing (undo swizzle at read)
    const int fr = lane & 15;
    const int gk = lane >> 4;
    const int xo0 = ((0 * 4 + gk) ^ (fr & 7)) * 8;    // ks=0
    const int xo1 = ((1 * 4 + gk) ^ (fr & 7)) * 8;    // ks=1
    const int arow = (wr * 128 + fr) * 64;            // ushort units (row stride 128B)
    const int brl  = (wc * 64 + fr) * 64;

    f32x4 acc[8][4] = {};
    bf16x8 ar[4][2], br[4][2];

    // ---- prologue: tile0 -> buf0, tile1 -> buf1; counted wait for tile0 only
    STAGEB(0, 1, 0); STAGEB(0, 0, 0); STAGEA(0, 1, 0); STAGEA(0, 0, 0);
    STAGEB(1, 1, 1); STAGEB(1, 0, 1); STAGEA(1, 1, 1); STAGEA(1, 0, 1);
    VMCNT8();
    BAR();

    // ---- window T: compute tile T from buf[PAR]; P4 stages tile T+2 into
    // buf[PAR] (free after P3: P3-end barrier orders all waves' LDS reads
    // before the gll issue; P4's quad is register-only), then vmcnt(8) waits
    // ONLY tile T+1's 8 loads (issued at window T-1's P4 -> 4-phase distance,
    // ~1300 cyc, covers HBM latency) while T+2's 8 stay in flight. (T4/m218)
#define WINDOW(PAR, STG, kt, VMSTMT) do { \
    /* P1 */ \
    loadAhalf(ar, Abuf[PAR], arow, xo0, xo1, 0); \
    loadBpair<0>(br, Bbuf[PAR], brl, xo0, xo1); \
    BAR(); quad<0, 0>(acc, ar, br); BAR(); \
    /* P2 */ \
    loadBpair<1>(br, Bbuf[PAR], brl, xo0, xo1); \
    BAR(); quad<0, 1>(acc, ar, br); BAR(); \
    /* P3 */ \
    loadAhalf(ar, Abuf[PAR], arow, xo0, xo1, 1); \
    BAR(); quad<1, 1>(acc, ar, br); BAR(); \
    /* P4 */ \
    if (STG) { STAGEB(kt, 1, PAR); STAGEB(kt, 0, PAR); \
               STAGEA(kt, 1, PAR); STAGEA(kt, 0, PAR); } \
    VMSTMT(); \
    BAR(); quad<1, 0>(acc, ar, br); BAR(); \
} while (0)

    for (int i = 0; i < (KTILES - 2) / 2; ++i) {   // T = 0..13, stage kt = T+2
        WINDOW(0, true, 2 * i + 2, VMCNT8);
        WINDOW(1, true, 2 * i + 3, VMCNT8);
    }
    WINDOW(0, false, 0, VMCNT0);   // T = 14: drain tile 15 (only 8 outstanding)
    WINDOW(1, false, 0, VMNONE);   // T = 15

#undef WINDOW
#undef STAGEA
#undef STAGEB

    // ---- epilogue: drain + LDS reuse
    __syncthreads();
    float* rowsum = (float*)&Abuf[0][0];   // [256][4]

    float bval[4];
    int   cls[4];
#pragma unroll
    for (int n = 0; n < 4; ++n) {
        cls[n]  = bcol + wc * 64 + n * 16 + fr;
        bval[n] = bias[cls[n]];
    }
#pragma unroll
    for (int m = 0; m < 8; ++m) {
#pragma unroll
        for (int j = 0; j < 4; ++j) {
            const int rl = wr * 128 + m * 16 + gk * 4 + j;   // C/D: row=(lane>>4)*4+j, col=fr
            long long tgt = target[brow + rl];
            float s = 0.f;
#pragma unroll
            for (int n = 0; n < 4; ++n) {
                float lg = acc[m][n][j] + bval[n];
                if (tgt == (long long)cls[n]) tlogit[brow + rl] = lg;
                s += __expf(lg);
            }
#pragma unroll
            for (int off = 1; off < 16; off <<= 1) s += __shfl_xor(s, off, 64);
            if (fr == 0) rowsum[rl * 4 + wc] = s;
        }
    }
    __syncthreads();
    if (tid < 256) {
        float v = rowsum[tid * 4 + 0] + rowsum[tid * 4 + 1]
                + rowsum[tid * 4 + 2] + rowsum[tid * 4 + 3];
        partials[(size_t)(brow + tid) * CTILES + ct] = v;
    }
}

__global__ void row_reduce(const float* __restrict__ partials,
                           const float* __restrict__ tlogit,
                           float* __restrict__ rowloss) {
    int lane = threadIdx.x & 63;
    int wid  = threadIdx.x >> 6;
    int row  = blockIdx.x * 4 + wid;
    const float* p = partials + (size_t)row * CTILES;
    float s = 0.f;
    for (int i = lane; i < CTILES; i += 64) s += p[i];
#pragma unroll
    for (int off = 1; off < 64; off <<= 1) s += __shfl_xor(s, off, 64);
    if (lane == 0) rowloss[row] = __logf(s) - tlogit[row];
}

__global__ void final_reduce(const float* __restrict__ rowloss, float* __restrict__ out) {
    __shared__ float red[256];
    int tid = threadIdx.x;
    float s = 0.f;
    for (int i = tid; i < NROWS; i += 256) s += rowloss[i];
    red[tid] = s;
    __syncthreads();
    for (int off = 128; off > 0; off >>= 1) {
        if (tid < off) red[tid] += red[tid + off];
        __syncthreads();
    }
    if (tid == 0) out[0] = red[0] * (1.0f / NROWS);
}

extern "C" void kernel_launch(void* const* d_in, const int* in_sizes, int n_in,
                              void* d_out, int out_size, void* d_ws, size_t ws_size,
                              hipStream_t stream) {
    const float*     features = (const float*)d_in[0];
    const long long* target   = (const long long*)d_in[1];
    const float*     weight   = (const float*)d_in[2];
    const float*     bias     = (const float*)d_in[3];
    float* out = (float*)d_out;

    char* ws = (char*)d_ws;
    size_t off = 0;
    unsigned short* fbf = (unsigned short*)(ws + off); off += (size_t)NROWS * DDIM * 2;   // 4 MB
    unsigned short* wbf = (unsigned short*)(ws + off); off += (size_t)NCLS * DDIM * 2;    // 262 MB
    float* partials     = (float*)(ws + off);          off += (size_t)NROWS * CTILES * 4; // 4 MB
    float* tlogit       = (float*)(ws + off);          off += (size_t)NROWS * 4;
    float* rowloss      = (float*)(ws + off);          off += (size_t)NROWS * 4;

    hipLaunchKernelGGL(convert_bf16, dim3(1024), dim3(256), 0, stream,
                       features, fbf, (long long)NROWS * (DDIM / 8));
    hipLaunchKernelGGL(convert_bf16, dim3(4096), dim3(256), 0, stream,
                       weight, wbf, (long long)NCLS * (DDIM / 8));
    hipLaunchKernelGGL(gemm8, dim3(RTILES * CTILES), dim3(512), 0, stream,
                       fbf, wbf, bias, target, partials, tlogit);
    hipLaunchKernelGGL(row_reduce, dim3(NROWS / 4), dim3(256), 0, stream,
                       partials, tlogit, rowloss);
    hipLaunchKernelGGL(final_reduce, dim3(1), dim3(256), 0, stream,
                       rowloss, out);
}